// Round 7
// baseline (22464.886 us; speedup 1.0000x reference)
//
#include <hip/hip_runtime.h>
#include <hip/hip_bf16.h>
#include <math.h>

#define N_NODES 50000
#define BB 16
#define LL 128
#define DD 64
#define E_N 200000
#define ET_N 100000
#define TEMPF 12.0f
#define DBLK 64
#define DNPB 782   // ceil(50000/64)

typedef unsigned long long ull;

__device__ __forceinline__ unsigned ordf(float f) {
  unsigned u = __float_as_uint(f);
  return (u & 0x80000000u) ? ~u : (u | 0x80000000u);
}

// ---------------- GNN phase (unchanged, harness-verified) ----------------

__global__ void k_node_enc(const float* __restrict__ nnf, const int* __restrict__ fid,
                           const float* __restrict__ femb, const float* __restrict__ W,
                           const float* __restrict__ bias, float* __restrict__ H) {
  __shared__ float sW[13 * 64];
  __shared__ float sF[80];
  __shared__ float sB[64];
  int tid = threadIdx.x;
  for (int i = tid; i < 13 * 64; i += 256) sW[i] = W[i];
  for (int i = tid; i < 80; i += 256) sF[i] = femb[i];
  if (tid < 64) sB[tid] = bias[tid];
  __syncthreads();
  int n = blockIdx.x * 4 + (tid >> 6);
  int d = tid & 63;
  if (n >= N_NODES) return;
  float acc = sB[d];
#pragma unroll
  for (int f = 0; f < 5; ++f) acc += nnf[n * 5 + f] * sW[f * 64 + d];
  int fl = fid[n];
#pragma unroll
  for (int j = 0; j < 8; ++j) acc += sF[fl * 8 + j] * sW[(5 + j) * 64 + d];
  H[n * 64 + d] = acc;
}

__global__ void k_edge_proj(const float* __restrict__ ea, const float* __restrict__ W1,
                            const float* __restrict__ b1, const float* __restrict__ W2,
                            const float* __restrict__ b2, float* __restrict__ Ee) {
  __shared__ float sW1[5 * 64];
  __shared__ float sB1[64];
  __shared__ float sW2[64 * 64];
  __shared__ float sB2[64];
  __shared__ float hid[4][64];
  int tid = threadIdx.x;
  for (int i = tid; i < 5 * 64; i += 256) sW1[i] = W1[i];
  for (int i = tid; i < 64 * 64; i += 256) sW2[i] = W2[i];
  if (tid < 64) { sB1[tid] = b1[tid]; sB2[tid] = b2[tid]; }
  __syncthreads();
  int w = tid >> 6, d = tid & 63;
  int e = blockIdx.x * 4 + w;
  float h = 0.f;
  if (e < E_N) {
    h = sB1[d];
#pragma unroll
    for (int f = 0; f < 5; ++f) h += ea[e * 5 + f] * sW1[f * 64 + d];
    h = fmaxf(h, 0.f);
  }
  hid[w][d] = h;
  __syncthreads();
  if (e >= E_N) return;
  float acc = sB2[d];
#pragma unroll 8
  for (int k = 0; k < 64; ++k) acc += hid[w][k] * sW2[k * 64 + d];
  Ee[e * 64 + d] = acc;
}

__global__ void k_gine_msg(const float* __restrict__ H, const float* __restrict__ Ee,
                           const int* __restrict__ ei, float* __restrict__ agg) {
  int tid = threadIdx.x;
  int e = blockIdx.x * 4 + (tid >> 6);
  int d = tid & 63;
  if (e >= E_N) return;
  int s = ei[e], t = ei[E_N + e];
  float m = fmaxf(H[s * 64 + d] + Ee[e * 64 + d], 0.f);
  atomicAdd(&agg[t * 64 + d], m);
}

__global__ __launch_bounds__(256) void k_gine_mlp(const float* __restrict__ H,
    const float* __restrict__ agg, const float* __restrict__ W1, const float* __restrict__ b1,
    const float* __restrict__ W2, const float* __restrict__ b2, float* __restrict__ Hout) {
  __shared__ float sW1[64 * 128];
  __shared__ float sW2[128 * 64];
  __shared__ float sB1[128];
  __shared__ float sB2[64];
  __shared__ float sx[2][64];
  __shared__ float sh[2][128];
  int tid = threadIdx.x;
  for (int i = tid; i < 64 * 128; i += 256) { sW1[i] = W1[i]; sW2[i] = W2[i]; }
  if (tid < 128) sB1[tid] = b1[tid];
  if (tid < 64) sB2[tid] = b2[tid];
  __syncthreads();
  int g = tid >> 7, j = tid & 127;
  const int ITER = 25;
  for (int it = 0; it < ITER; ++it) {
    int n = (blockIdx.x + it * 1024) * 2 + g;
    if (j < 64 && n < N_NODES) sx[g][j] = H[n * 64 + j] + agg[n * 64 + j];
    __syncthreads();
    float hj = 0.f;
    if (n < N_NODES) {
      hj = sB1[j];
#pragma unroll 8
      for (int k = 0; k < 64; ++k) hj += sx[g][k] * sW1[k * 128 + j];
      hj = fmaxf(hj, 0.f);
    }
    sh[g][j] = hj;
    __syncthreads();
    if (j < 64 && n < N_NODES) {
      float acc = sB2[j];
#pragma unroll 8
      for (int k = 0; k < 128; ++k) acc += sh[g][k] * sW2[k * 64 + j];
      Hout[n * 64 + j] = fmaxf(acc, 0.f);
    }
    __syncthreads();
  }
}

__global__ void k_l2n(const float* __restrict__ H, float* __restrict__ Hn) {
  int tid = threadIdx.x;
  int n = blockIdx.x * 4 + (tid >> 6);
  int d = tid & 63;
  if (n >= N_NODES) return;
  float v = H[n * 64 + d];
  float ss = v * v;
#pragma unroll
  for (int o = 32; o > 0; o >>= 1) ss += __shfl_xor(ss, o, 64);
  float nr = fmaxf(sqrtf(ss), 1e-12f);
  Hn[n * 64 + d] = v / nr;
}

__global__ void k_traj_msg(const float* __restrict__ Hn, const int* __restrict__ tei,
                           const float* __restrict__ tw, float* __restrict__ agg) {
  int tid = threadIdx.x;
  int e = blockIdx.x * 4 + (tid >> 6);
  int d = tid & 63;
  if (e >= ET_N) return;
  int s = tei[e], t = tei[ET_N + e];
  atomicAdd(&agg[t * 64 + d], tw[e] * Hn[s * 64 + d]);
}

__global__ void k_traj_mlp(const float* __restrict__ Hn, const float* __restrict__ agg,
                           const float* __restrict__ Wt, const float* __restrict__ bt,
                           float* __restrict__ HR) {
  __shared__ float sW[64 * 64];
  __shared__ float sB[64];
  __shared__ float sx[4][64];
  int tid = threadIdx.x;
  for (int i = tid; i < 4096; i += 256) sW[i] = Wt[i];
  if (tid < 64) sB[tid] = bt[tid];
  __syncthreads();
  int w = tid >> 6, d = tid & 63;
  int n = blockIdx.x * 4 + w;
  if (n < N_NODES) sx[w][d] = Hn[n * 64 + d] + agg[n * 64 + d];
  __syncthreads();
  if (n >= N_NODES) return;
  float acc = sB[d];
#pragma unroll 8
  for (int k = 0; k < 64; ++k) acc += sx[w][k] * sW[k * 64 + d];
  acc = fmaxf(acc, 0.f);
  float ss = acc * acc;
#pragma unroll
  for (int o = 32; o > 0; o >>= 1) ss += __shfl_xor(ss, o, 64);
  float nr = fmaxf(sqrtf(ss), 1e-12f);
  HR[n * 64 + d] = acc / nr;
}

// ---------------- Encoder phase (unchanged) ----------------

__global__ __launch_bounds__(192) void k_gi(const int* __restrict__ pred,
    const int* __restrict__ lens, const float* __restrict__ HR,
    const float* __restrict__ Wf, const float* __restrict__ bf,
    const float* __restrict__ Wb, const float* __restrict__ bb,
    float* __restrict__ gif, float* __restrict__ gib) {
  __shared__ float xf[64];
  __shared__ float xb[64];
  int bid = blockIdx.x;
  int b = bid >> 7, t = bid & 127;
  int len = lens[b];
  int tid = threadIdx.x;
  bool act = (t < len);
  if (act && tid < 64) {
    int idx = pred[b * 128 + t];
    xf[tid] = HR[idx * 64 + tid];
    int idxb = pred[b * 128 + (len - 1 - t)];
    xb[tid] = HR[idxb * 64 + tid];
  }
  __syncthreads();
  if (!act) return;
  int j = tid;
  float a1 = bf[j], a2 = bb[j];
#pragma unroll 8
  for (int k = 0; k < 64; ++k) {
    a1 += xf[k] * Wf[k * 192 + j];
    a2 += xb[k] * Wb[k * 192 + j];
  }
  gif[(b * 128 + t) * 192 + j] = a1;
  gib[(b * 128 + t) * 192 + j] = a2;
}

__global__ __launch_bounds__(192, 1) void k_gru(const float* __restrict__ gif,
    const float* __restrict__ gib, const float* __restrict__ Whf, const float* __restrict__ bhf,
    const float* __restrict__ Whb, const float* __restrict__ bhb, const int* __restrict__ lens,
    float* __restrict__ outf, float* __restrict__ outb) {
  __shared__ __align__(16) float h[64];
  __shared__ float s[192];
  __shared__ float ghn[64];
  int bid = blockIdx.x;
  int dir = bid >> 4, b = bid & 15;
  const float* gi = dir ? gib : gif;
  const float* Whh = dir ? Whb : Whf;
  const float* bhh = dir ? bhb : bhf;
  float* out = dir ? outb : outf;
  int len = lens[b];
  int j = threadIdx.x;
  float w[64];
#pragma unroll
  for (int k = 0; k < 64; ++k) w[k] = Whh[k * 192 + j];
  float bj = bhh[j];
  if (j < 64) h[j] = 0.f;
  __syncthreads();
  for (int t = 0; t < len; ++t) {
    float gij = gi[(b * 128 + t) * 192 + j];
    float gh = bj;
    const float4* h4 = (const float4*)h;
#pragma unroll
    for (int k4 = 0; k4 < 16; ++k4) {
      float4 hv = h4[k4];
      gh += hv.x * w[4 * k4] + hv.y * w[4 * k4 + 1] + hv.z * w[4 * k4 + 2] + hv.w * w[4 * k4 + 3];
    }
    if (j < 128) s[j] = gij + gh;
    else { s[j] = gij; ghn[j - 128] = gh; }
    __syncthreads();
    if (j < 64) {
      float r = 1.f / (1.f + expf(-s[j]));
      float z = 1.f / (1.f + expf(-s[64 + j]));
      float n = tanhf(s[128 + j] + r * ghn[j]);
      float hn = (1.f - z) * n + z * h[j];
      h[j] = hn;
      int tt = dir ? (len - 1 - t) : t;
      out[(b * 128 + tt) * 64 + j] = hn;
    }
    __syncthreads();
  }
  int total = (128 - len) * 64;
  for (int idx = j; idx < total; idx += 192) {
    int t2 = len + (idx >> 6), d = idx & 63;
    out[(b * 128 + t2) * 64 + d] = 0.f;
  }
}

__global__ void k_encout(const float* __restrict__ outf, const float* __restrict__ outb,
                         const float* __restrict__ Wep, const float* __restrict__ bep,
                         float* __restrict__ enc, float* __restrict__ encT) {
  __shared__ float cat[128];
  int bid = blockIdx.x;
  int b = bid >> 7, t = bid & 127;
  int d = threadIdx.x;  // 64 threads
  cat[d] = outf[bid * 64 + d];
  cat[64 + d] = outb[bid * 64 + d];
  __syncthreads();
  float acc = bep[d];
#pragma unroll 8
  for (int jj = 0; jj < 128; ++jj) acc += cat[jj] * Wep[jj * 64 + d];
  float ss = acc * acc;
#pragma unroll
  for (int o = 32; o > 0; o >>= 1) ss += __shfl_xor(ss, o, 64);
  float nr = fmaxf(sqrtf(ss), 1e-12f);
  float y = acc / nr;
  enc[bid * 64 + d] = y;
  encT[(b * 64 + d) * 128 + t] = y;
}

__global__ void k_encmean(const float* __restrict__ enc, const int* __restrict__ lens,
                          float* __restrict__ h_g) {
  int tid = threadIdx.x;  // 1024
  int b = tid >> 6, d = tid & 63;
  int len = lens[b];
  float s = 0.f;
  for (int t = 0; t < len; ++t) s += enc[(b * 128 + t) * 64 + d];
  h_g[b * 64 + d] = s / (float)len;
}

// ---------------- Decoder v4: ONE kernel per step, dec_a replicated ----------------
// 64 blocks x 256 threads. Every block deterministically recomputes the full
// per-step recurrent state (argmax-reduce, GRU, attention, z) from global state
// written by the PREVIOUS step's kernel (parity double-buffered) -- identical
// inputs give bit-identical results in all blocks, so cross-block writes of h
// are benign identical-value races. Then each block computes logits+argmax for
// its private 782-node slice. No atomics, no spins, no cross-block sync.

__global__ __launch_bounds__(256) void k_dec(
    const float* __restrict__ HR, const float* __restrict__ enc, const float* __restrict__ encT,
    const float* __restrict__ Wih, const float* __restrict__ Whh,
    const float* __restrict__ bih, const float* __restrict__ bhh,
    const float* __restrict__ Wdo, const float* __restrict__ bdo,
    const int* __restrict__ lens, float* __restrict__ h_g,
    float* __restrict__ logits, ull* __restrict__ slots, int t) {
  __shared__ float xT[64][16];     // x[d][b]
  __shared__ float hT[64][16];     // h[d][b]
  __shared__ float sS[16][193];    // gi (+gh)
  __shared__ float sGhn[16][65];
  __shared__ float aSc[16][129];   // scores -> softmax weights
  __shared__ __align__(16) float ctxS[16][64];
  __shared__ __align__(16) float zS[16][64];
  __shared__ int widx[16];
  __shared__ int lenS[16];
  __shared__ ull r16[16][16];
  __shared__ ull redS[4][16];

  const int bid = blockIdx.x, tid = threadIdx.x;
  const int rpar = t & 1, wpar = rpar ^ 1;
  const float* hin = h_g + rpar * 1024;
  float* hout = h_g + wpar * 1024;
  const ull* slr = slots + rpar * 1024;
  ull* slw = slots + wpar * 1024;

  if (tid < 16) lenS[tid] = lens[tid];

  // ---- Phase R: global argmax of previous step from 64 partials per b ----
  if (t > 0) {
    {
      const int b = tid >> 4, i0 = tid & 15;
      const ull* sb = slr + b * 64;
      ull k0 = sb[i0], k1 = sb[i0 + 16], k2 = sb[i0 + 32], k3 = sb[i0 + 48];
      ull k = k0 > k1 ? k0 : k1;
      ull k23 = k2 > k3 ? k2 : k3;
      k = k > k23 ? k : k23;
      r16[b][i0] = k;
    }
    __syncthreads();
    if (tid < 16) {
      ull m = r16[tid][0];
#pragma unroll
      for (int i = 1; i < 16; ++i) m = r16[tid][i] > m ? r16[tid][i] : m;
      unsigned w = 0xFFFFFFFFu - (unsigned)(m & 0xFFFFFFFFull);
      widx[tid] = (int)(w < (unsigned)N_NODES ? w : (unsigned)(N_NODES - 1));
    }
    __syncthreads();
  }

  // ---- Phase G: gather x = HR[widx[b]] (0 at t==0), load h; store transposed ----
  for (int k = 0; k < 4; ++k) {
    int idx = tid + 256 * k;           // 1024 items, b-fast
    int b = idx & 15, d = idx >> 4;
    float xv = 0.f;
    if (t > 0) xv = HR[(size_t)widx[b] * 64 + d];
    xT[d][b] = xv;
    hT[d][b] = hin[b * 64 + d];
  }
  __syncthreads();

  // ---- Phase 1: gi = x@Wih + bih ; gh = h@Whh + bhh (192 threads, 16 b each) ----
  if (tid < 192) {
    {
      float bi = bih[tid];
      float acc[16];
#pragma unroll
      for (int b = 0; b < 16; ++b) acc[b] = bi;
#pragma unroll
      for (int k = 0; k < 64; ++k) {
        float wk = Wih[k * 192 + tid];
        const float4* xp = (const float4*)&xT[k][0];
        float4 x0 = xp[0], x1 = xp[1], x2 = xp[2], x3 = xp[3];
        acc[0] += x0.x * wk; acc[1] += x0.y * wk; acc[2] += x0.z * wk; acc[3] += x0.w * wk;
        acc[4] += x1.x * wk; acc[5] += x1.y * wk; acc[6] += x1.z * wk; acc[7] += x1.w * wk;
        acc[8] += x2.x * wk; acc[9] += x2.y * wk; acc[10] += x2.z * wk; acc[11] += x2.w * wk;
        acc[12] += x3.x * wk; acc[13] += x3.y * wk; acc[14] += x3.z * wk; acc[15] += x3.w * wk;
      }
#pragma unroll
      for (int b = 0; b < 16; ++b) sS[b][tid] = acc[b];
    }
    {
      float bh = bhh[tid];
      float acc[16];
#pragma unroll
      for (int b = 0; b < 16; ++b) acc[b] = bh;
#pragma unroll
      for (int k = 0; k < 64; ++k) {
        float wk = Whh[k * 192 + tid];
        const float4* hp = (const float4*)&hT[k][0];
        float4 x0 = hp[0], x1 = hp[1], x2 = hp[2], x3 = hp[3];
        acc[0] += x0.x * wk; acc[1] += x0.y * wk; acc[2] += x0.z * wk; acc[3] += x0.w * wk;
        acc[4] += x1.x * wk; acc[5] += x1.y * wk; acc[6] += x1.z * wk; acc[7] += x1.w * wk;
        acc[8] += x2.x * wk; acc[9] += x2.y * wk; acc[10] += x2.z * wk; acc[11] += x2.w * wk;
        acc[12] += x3.x * wk; acc[13] += x3.y * wk; acc[14] += x3.z * wk; acc[15] += x3.w * wk;
      }
      if (tid < 128) {
#pragma unroll
        for (int b = 0; b < 16; ++b) sS[b][tid] += acc[b];
      } else {
#pragma unroll
        for (int b = 0; b < 16; ++b) sGhn[b][tid - 128] = acc[b];
      }
    }
  }
  __syncthreads();

  // ---- Phase 2: GRU elementwise; update hT, write hout ----
  for (int k = 0; k < 4; ++k) {
    int idx = tid + 256 * k;
    int b = idx & 15, d = idx >> 4;
    float r = 1.f / (1.f + expf(-sS[b][d]));
    float zz = 1.f / (1.f + expf(-sS[b][64 + d]));
    float nn = tanhf(sS[b][128 + d] + r * sGhn[b][d]);
    float hn = (1.f - zz) * nn + zz * hT[d][b];
    hT[d][b] = hn;
    hout[b * 64 + d] = hn;
  }
  __syncthreads();

  // ---- Phase 3: attention scores (float4 over l) ----
  for (int k = 0; k < 2; ++k) {
    int item = tid + 256 * k;          // 512 items: (b, lq)
    int b = item >> 5, lq = item & 31;
    int l0 = lq * 4;
    float4 s4 = make_float4(0.f, 0.f, 0.f, 0.f);
    const float4* eT = (const float4*)(encT + b * 8192 + l0);
    for (int d2 = 0; d2 < 64; ++d2) {
      float hd = hT[d2][b];
      float4 ev = eT[d2 * 32];
      s4.x += hd * ev.x; s4.y += hd * ev.y; s4.z += hd * ev.z; s4.w += hd * ev.w;
    }
    int len = lenS[b];
    aSc[b][l0 + 0] = (l0 + 0 < len) ? s4.x : -1e9f;
    aSc[b][l0 + 1] = (l0 + 1 < len) ? s4.y : -1e9f;
    aSc[b][l0 + 2] = (l0 + 2 < len) ? s4.z : -1e9f;
    aSc[b][l0 + 3] = (l0 + 3 < len) ? s4.w : -1e9f;
  }
  __syncthreads();

  // ---- Phase 4: softmax per b (wave-local, 16 lanes per b) ----
  {
    const int w = tid >> 6, lane = tid & 63;
    const int b = w * 4 + (lane >> 4), sub = lane & 15;
    float mx = -1e30f;
#pragma unroll
    for (int i = 0; i < 8; ++i) mx = fmaxf(mx, aSc[b][sub + 16 * i]);
#pragma unroll
    for (int o = 1; o < 16; o <<= 1) mx = fmaxf(mx, __shfl_xor(mx, o, 64));
    float pv[8];
    float sm = 0.f;
#pragma unroll
    for (int i = 0; i < 8; ++i) {
      float p = expf(aSc[b][sub + 16 * i] - mx);
      pv[i] = p; sm += p;
    }
#pragma unroll
    for (int o = 1; o < 16; o <<= 1) sm += __shfl_xor(sm, o, 64);
    float inv = 1.f / sm;
#pragma unroll
    for (int i = 0; i < 8; ++i) aSc[b][sub + 16 * i] = pv[i] * inv;
  }
  __syncthreads();

  // ---- Phase 5: context (float4 over d; one item per thread) ----
  {
    int b = tid >> 4, dq = tid & 15;
    float4 cx = make_float4(0.f, 0.f, 0.f, 0.f);
    const float4* eb = (const float4*)(enc + b * 8192 + dq * 4);
    for (int l = 0; l < 128; ++l) {
      float av = aSc[b][l];
      float4 ev = eb[l * 16];
      cx.x += av * ev.x; cx.y += av * ev.y; cx.z += av * ev.z; cx.w += av * ev.w;
    }
    *(float4*)(&ctxS[b][dq * 4]) = cx;
  }
  __syncthreads();

  // ---- Phase 6: z = l2n([h,ctx] @ Wdo + bdo); per-b l2-norm within a wave ----
  for (int k = 0; k < 4; ++k) {
    int b = (tid >> 6) + 4 * k;
    int d = tid & 63;
    float acc = bdo[d];
    for (int j = 0; j < 64; ++j) acc += hT[j][b] * Wdo[j * 64 + d];
    for (int j = 0; j < 64; ++j) acc += ctxS[b][j] * Wdo[(64 + j) * 64 + d];
    float ss = acc * acc;
#pragma unroll
    for (int o = 32; o > 0; o >>= 1) ss += __shfl_xor(ss, o, 64);
    float nr = fmaxf(sqrtf(ss), 1e-12f);
    zS[b][d] = acc / nr;
  }
  __syncthreads();

  // ---- Phase 7: logits + per-b argmax over this block's node slice ----
  const int n0 = bid * DNPB;
  const int n1 = min(n0 + DNPB, N_NODES);
  ull best[16];
#pragma unroll
  for (int b = 0; b < 16; ++b) best[b] = 0ull;
  float* lrow = logits + (size_t)t * 50000u;
  for (int it = 0; it < 4; ++it) {
    int n = n0 + it * 256 + tid;
    if (n < n1) {
      const float4* hp = (const float4*)(HR + (size_t)n * 64);
      float4 hv[16];
#pragma unroll
      for (int q = 0; q < 16; ++q) hv[q] = hp[q];
#pragma unroll
      for (int b = 0; b < 16; ++b) {
        const float4* zp = (const float4*)(&zS[b][0]);
        float acc = 0.f;
#pragma unroll
        for (int q = 0; q < 16; ++q) {
          float4 zv = zp[q];
          acc += hv[q].x * zv.x + hv[q].y * zv.y + hv[q].z * zv.z + hv[q].w * zv.w;
        }
        float lg = TEMPF * acc;
        __builtin_nontemporal_store(lg, lrow + (size_t)b * 6400000u + n);
        ull key = ((ull)ordf(lg) << 32) | (ull)(0xFFFFFFFFu - (unsigned)n);
        best[b] = key > best[b] ? key : best[b];
      }
    }
  }
  const int wv = tid >> 6;
#pragma unroll
  for (int b = 0; b < 16; ++b) {
    ull k = best[b];
#pragma unroll
    for (int o = 32; o > 0; o >>= 1) {
      ull other = __shfl_xor(k, o, 64);
      k = k > other ? k : other;
    }
    if ((tid & 63) == 0) redS[wv][b] = k;
  }
  __syncthreads();
  if (tid < 16) {
    ull m = redS[0][tid];
    m = redS[1][tid] > m ? redS[1][tid] : m;
    m = redS[2][tid] > m ? redS[2][tid] : m;
    m = redS[3][tid] > m ? redS[3][tid] : m;
    slw[tid * 64 + bid] = m;
  }
}

// ---------------- launch ----------------

extern "C" void kernel_launch(void* const* d_in, const int* in_sizes, int n_in,
                              void* d_out, int out_size, void* d_ws, size_t ws_size,
                              hipStream_t stream) {
  const int* pred = (const int*)d_in[0];
  const int* lens = (const int*)d_in[1];
  const float* nnf = (const float*)d_in[2];
  const int* fid = (const int*)d_in[3];
  const int* ei = (const int*)d_in[4];
  const float* ea = (const float*)d_in[5];
  const int* tei = (const int*)d_in[6];
  const float* tw = (const float*)d_in[7];
  const float* femb = (const float*)d_in[8];
  const float* W_ne = (const float*)d_in[9];  const float* b_ne = (const float*)d_in[10];
  const float* W_e1 = (const float*)d_in[11]; const float* b_e1 = (const float*)d_in[12];
  const float* W_e2 = (const float*)d_in[13]; const float* b_e2 = (const float*)d_in[14];
  const float* g1W1 = (const float*)d_in[15]; const float* g1b1 = (const float*)d_in[16];
  const float* g1W2 = (const float*)d_in[17]; const float* g1b2 = (const float*)d_in[18];
  const float* g2W1 = (const float*)d_in[19]; const float* g2b1 = (const float*)d_in[20];
  const float* g2W2 = (const float*)d_in[21]; const float* g2b2 = (const float*)d_in[22];
  const float* W_t = (const float*)d_in[23];  const float* b_t = (const float*)d_in[24];
  const float* Wihf = (const float*)d_in[25]; const float* Whhf = (const float*)d_in[26];
  const float* bihf = (const float*)d_in[27]; const float* bhhf = (const float*)d_in[28];
  const float* Wihb = (const float*)d_in[29]; const float* Whhb = (const float*)d_in[30];
  const float* bihb = (const float*)d_in[31]; const float* bhhb = (const float*)d_in[32];
  const float* W_ep = (const float*)d_in[33]; const float* b_ep = (const float*)d_in[34];
  const float* Wihd = (const float*)d_in[35]; const float* Whhd = (const float*)d_in[36];
  const float* bihd = (const float*)d_in[37]; const float* bhhd = (const float*)d_in[38];
  const float* W_do = (const float*)d_in[39]; const float* b_do = (const float*)d_in[40];

  float* out = (float*)d_out;
  float* logits = out;
  float* HR = out + 102400000;  // second output

  // large scratch lives in the (not-yet-written) logits region
  float* Ee    = out + 0;
  float* H_a   = out + 12800000;
  float* H_b   = out + 16000000;
  float* agg   = out + 19200000;
  float* HRt   = out + 22400000;
  float* gi_f  = out + 25600000;
  float* gi_b  = out + 26000000;
  float* out_f = out + 26400000;
  float* out_b = out + 26600000;

  // decode-live scratch in d_ws
  char* w8 = (char*)d_ws;
  ull* slots = (ull*)w8;                                   // 2*16*64*8 = 16 KB
  float* h_g = (float*)(w8 + 16384);                       // 2*1024*4 = 8 KB
  float* enc = (float*)(w8 + 16384 + 8192);                // 512 KB
  float* encT = enc + 131072;                              // 512 KB

  k_node_enc<<<12500, 256, 0, stream>>>(nnf, fid, femb, W_ne, b_ne, H_a);
  k_edge_proj<<<50000, 256, 0, stream>>>(ea, W_e1, b_e1, W_e2, b_e2, Ee);

  hipMemsetAsync(agg, 0, (size_t)N_NODES * 64 * 4, stream);
  k_gine_msg<<<50000, 256, 0, stream>>>(H_a, Ee, ei, agg);
  k_gine_mlp<<<1024, 256, 0, stream>>>(H_a, agg, g1W1, g1b1, g1W2, g1b2, H_b);

  hipMemsetAsync(agg, 0, (size_t)N_NODES * 64 * 4, stream);
  k_gine_msg<<<50000, 256, 0, stream>>>(H_b, Ee, ei, agg);
  k_gine_mlp<<<1024, 256, 0, stream>>>(H_b, agg, g2W1, g2b1, g2W2, g2b2, H_a);

  k_l2n<<<12500, 256, 0, stream>>>(H_a, HRt);

  hipMemsetAsync(agg, 0, (size_t)N_NODES * 64 * 4, stream);
  k_traj_msg<<<25000, 256, 0, stream>>>(HRt, tei, tw, agg);
  k_traj_mlp<<<12500, 256, 0, stream>>>(HRt, agg, W_t, b_t, HR);

  k_gi<<<2048, 192, 0, stream>>>(pred, lens, HR, Wihf, bihf, Wihb, bihb, gi_f, gi_b);
  k_gru<<<32, 192, 0, stream>>>(gi_f, gi_b, Whhf, bhhf, Whhb, bhhb, lens, out_f, out_b);
  k_encout<<<2048, 64, 0, stream>>>(out_f, out_b, W_ep, b_ep, enc, encT);
  k_encmean<<<1, 1024, 0, stream>>>(enc, lens, h_g);

  for (int t = 0; t < 128; ++t) {
    k_dec<<<DBLK, 256, 0, stream>>>(HR, enc, encT, Wihd, Whhd, bihd, bhhd, W_do, b_do,
                                    lens, h_g, logits, slots, t);
  }
}